// Round 13
// baseline (257.031 us; speedup 1.0000x reference)
//
#include <hip/hip_runtime.h>
#include <stdint.h>
#include <stddef.h>

// Problem: X=2048, Y=256, F=128, H=8, NF=32, O=H*NF=256. f32 I/O, mask int32.
//
// Round 13 = round 12 + scheduling-scope clamp:
//  - #pragma clang loop unroll(disable) on the xi loop: the compiler was fully
//    unrolling XPB=8 and software-pipelining across x's, hoisting next-x loads
//    into the acc-live region -> the persistent ~73 MB scratch spill (r9-r12).
//  - convert loads are per-kk transients (f32x8 dies into ah[kk] immediately).
//  - otherwise identical to round 12: 32x32x16 GEMM (verified mappings),
//    streamed epilogue, 3 barriers/x, 0.64 MB/x block LDS traffic.

typedef __attribute__((ext_vector_type(8)))  _Float16 f16x8;   // 4 VGPRs
typedef __attribute__((ext_vector_type(8)))  float f32x8;
typedef __attribute__((ext_vector_type(4)))  float f32x4;
typedef __attribute__((ext_vector_type(16))) float f32x16;

#define XPB 8
#define NBLK 256

// dynamic LDS layout (bytes) — total 158816 < 163840
#define OFF_W1   0u        // 65536: W1 f16 frags [(ct*8+ks)][l][8]: col=ct*32+(l&31), k=ks*16+(l>>5)*8+j
#define OFF_W2   65536u    // 4096 : W2 f16 frags [kk][l][8] (16x16 layout, cols 8..15 = 0)
#define OFF_A    69632u    // 65536: A  f16 frags [(rt2*8+ks)][l][8]: row=rt2*32+(l&31), k=ks*16+(l>>5)*8+j
#define OFF_COEF 135168u   // 8224 : float[8][257] logits -> coefs (head-major, padded)
#define OFF_OUTP 143392u   // 8192 : float[16][128] per-wave output partials
#define OFF_SNQ  151584u   // 4096 : float snqS[256][2], snqQ[256][2]
#define OFF_B1   155680u   // 1024 : float[256]
#define OFF_G    156704u   // 1024
#define OFF_BT   157728u   // 1024
#define OFF_B2   158752u   // 64   : float[16]
#define LDS_BYTES 158816u

__device__ __forceinline__ f32x4 mfma16(f16x8 a, f16x8 b, f32x4 c){
  return __builtin_amdgcn_mfma_f32_16x16x32_f16(a, b, c, 0, 0, 0);
}
__device__ __forceinline__ f32x16 mfma32(f16x8 a, f16x8 b, f32x16 c){
  return __builtin_amdgcn_mfma_f32_32x32x16_f16(a, b, c, 0, 0, 0);
}

__global__ __launch_bounds__(1024, 4) void attn_main(
    const float* __restrict__ xy, const int* __restrict__ mask,
    const float* __restrict__ W1g, const float* __restrict__ b1g,
    const float* __restrict__ gammag, const float* __restrict__ betag,
    const float* __restrict__ W2g, const float* __restrict__ b2g,
    float* __restrict__ out)
{
  extern __shared__ char smem[];
  const int tid = threadIdx.x;
  const int l  = tid & 63;
  const int w  = tid >> 6;     // wave 0..15
  const int rg = w >> 1;       // GEMM row group: rows [32rg, 32rg+32)
  const int cg = w & 1;        // GEMM col group: cols [128cg, 128cg+128)
  const int lg = l >> 4;       // lane group 0..3 (16x16 phases)
  const int lc = l & 15;
  const int c32 = l & 31;      // 32x32 col-in-tile
  const int hi5 = l >> 5;      // 32x32 row-group select

  _Float16* w1f = (_Float16*)(smem + OFF_W1);
  _Float16* w2f = (_Float16*)(smem + OFF_W2);
  _Float16* af  = (_Float16*)(smem + OFF_A);
  float* coefT = (float*)(smem + OFF_COEF);           // [8][257]
  float* outp  = (float*)(smem + OFF_OUTP);           // [16][128]
  float* snqS  = (float*)(smem + OFF_SNQ);            // [256][2]
  float* snqQ  = (float*)(smem + OFF_SNQ + 2048u);    // [256][2]
  float* ldsB1 = (float*)(smem + OFF_B1);
  float* ldsG  = (float*)(smem + OFF_G);
  float* ldsBt = (float*)(smem + OFF_BT);
  float* ldsB2 = (float*)(smem + OFF_B2);

  if (tid < 256){
    ldsB1[tid] = b1g[tid];
    ldsG[tid]  = gammag[tid];
    ldsBt[tid] = betag[tid];
  }
  if (tid < 16) ldsB2[tid] = (tid < 8) ? b2g[tid] : 0.f;

  // ---- gather W1 (f32) -> f16 32x32 fragment order:
  //      eb = (ct*8+ks)*64+l; value j: W1[f][o], f=ks*16+(l>>5)*8+j, o=ct*32+(l&31)
  #pragma unroll
  for (int i = 0; i < 4; ++i){
    int eb = i * 1024 + tid;
    int bl = eb & 63;
    int ks = (eb >> 6) & 7;
    int ct = eb >> 9;
    int o  = ct * 32 + (bl & 31);
    int f0 = ks * 16 + ((bl >> 5) << 3);
    f16x8 v;
    #pragma unroll
    for (int j = 0; j < 8; ++j) v[j] = (_Float16)W1g[(size_t)(f0 + j) * 256 + o];
    *(f16x8*)(w1f + eb * 8) = v;
  }
  // ---- gather W2 -> f16 16x16 fragments (pad cols 8..15 with zero) ----
  if (tid < 256){
    int eb  = tid;
    int bl  = eb & 63;
    int bkk = eb >> 6;
    int h   = bl & 15;
    int f0  = bkk * 32 + ((bl >> 4) << 3);
    f16x8 v;
    #pragma unroll
    for (int j = 0; j < 8; ++j)
      v[j] = (h < 8) ? (_Float16)W2g[(size_t)(f0 + j) * 8 + h] : (_Float16)0.f;
    *(f16x8*)(w2f + eb * 8) = v;
  }
  __syncthreads();   // gathers + params visible

  const int x0 = blockIdx.x * XPB;

  #pragma clang loop unroll(disable)
  for (int xi = 0; xi < XPB; ++xi){
    const int x = x0 + xi;

    // ---- convert: wave w handles rows [16w,16w+16); per-kk transient load ----
    f16x8 ah[4];
    #pragma unroll
    for (int kk = 0; kk < 4; ++kk){
      f32x8 v = *(const f32x8*)(xy + (((size_t)x * 256 + w * 16 + lc) << 7)
                                   + kk * 32 + (lg << 3));
      f16x8 vh;
      #pragma unroll
      for (int j = 0; j < 8; ++j){
        float f = fmaxf(v[j], 0.f) + 0.01f * fminf(v[j], 0.f);
        vh[j] = (_Float16)f;
      }
      ah[kk] = vh;
      // 32x32 A fragment store (verified r11): rt2=w>>1; ks=2*kk+(lg>>1);
      // l'=32*(lg&1)+16*(w&1)+lc
      *(f16x8*)(af + ((((w >> 1) * 8 + 2 * kk + (lg >> 1)) * 64
                       + 32 * (lg & 1) + 16 * (w & 1) + lc) * 8)) = vh;
    }
    int mk[4];
    if (w < 8){
      #pragma unroll
      for (int k = 0; k < 4; ++k) mk[k] = mask[(x << 8) + (k << 6) + l];
    }

    // ---- logits for rows [16w,16w+16): 4 x 16x16 MFMA from regs ----
    {
      f32x4 la = {0.f,0.f,0.f,0.f};
      #pragma unroll
      for (int kk = 0; kk < 4; ++kk){
        f16x8 wb = *(const f16x8*)(w2f + (kk * 64 + l) * 8);
        la = mfma16(ah[kk], wb, la);
      }
      if (lc < 8){
        float b2v = ldsB2[lc];
        #pragma unroll
        for (int r = 0; r < 4; ++r){
          int row = (w << 4) + (lg << 2) + r;   // 16x16 C/D: row=(l>>4)*4+r, col=l&15
          coefT[lc * 257 + row] = la[r] + b2v;
        }
      }
    }
    __syncthreads();   // B1: A fragments + all logits visible

    // ---- softmax over Y for head w (waves 0-7; mask-fill logits with 0);
    //      other waves proceed to GEMM -> softmax latency overlapped ----
    if (w < 8){
      float lgv[4];
      #pragma unroll
      for (int k = 0; k < 4; ++k){
        float v = coefT[w * 257 + (k << 6) + l];
        lgv[k] = mk[k] ? 0.f : v;
      }
      float mx = fmaxf(fmaxf(lgv[0], lgv[1]), fmaxf(lgv[2], lgv[3]));
      #pragma unroll
      for (int mm = 1; mm < 64; mm <<= 1) mx = fmaxf(mx, __shfl_xor(mx, mm));
      float e[4]; float sum = 0.f;
      #pragma unroll
      for (int k = 0; k < 4; ++k){ e[k] = __expf(lgv[k] - mx); sum += e[k]; }
      #pragma unroll
      for (int mm = 1; mm < 64; mm <<= 1) sum += __shfl_xor(sum, mm);
      float inv = 1.f / sum;
      #pragma unroll
      for (int k = 0; k < 4; ++k) coefT[w * 257 + (k << 6) + l] = e[k] * inv;
    }

    // ---- GEMM 32x32x16: acc[ct4], rows 32rg+..., cols 128cg+32ct4+c32 ----
    f32x16 acc[4];
    #pragma unroll
    for (int ct4 = 0; ct4 < 4; ++ct4)
      #pragma unroll
      for (int r = 0; r < 16; ++r) acc[ct4][r] = 0.f;

    #pragma unroll
    for (int ks = 0; ks < 8; ++ks){
      f16x8 a = *(const f16x8*)(af + ((rg * 8 + ks) * 64 + l) * 8);
      #pragma unroll
      for (int ct4 = 0; ct4 < 4; ++ct4){
        f16x8 b = *(const f16x8*)(w1f + (((cg * 4 + ct4) * 8 + ks) * 64 + l) * 8);
        acc[ct4] = mfma32(a, b, acc[ct4]);
      }
    }

    // ---- hid = acc + b1 (per col-tile), then STREAMED per-row-slot stats:
    //      C/D 32x32: col=128cg+32ct4+c32, row=32rg+(r&3)+8*(r>>2)+4*hi5 ----
    #pragma unroll
    for (int ct4 = 0; ct4 < 4; ++ct4){
      float bv = ldsB1[cg * 128 + ct4 * 32 + c32];
      #pragma unroll
      for (int r = 0; r < 16; ++r) acc[ct4][r] += bv;
    }
    #pragma unroll
    for (int r = 0; r < 16; ++r){
      float a0 = acc[0][r], a1 = acc[1][r], a2 = acc[2][r], a3 = acc[3][r];
      float s = (a0 + a1) + (a2 + a3);
      float q = fmaf(a0, a0, fmaf(a1, a1, fmaf(a2, a2, a3 * a3)));
      #pragma unroll
      for (int mm = 1; mm <= 16; mm <<= 1){
        s += __shfl_xor(s, mm);
        q += __shfl_xor(q, mm);
      }
      if (c32 == 0){
        int row = rg * 32 + (r & 3) + ((r >> 2) << 3) + (hi5 << 2);
        snqS[row * 2 + cg] = s;
        snqQ[row * 2 + cg] = q;
      }
    }
    __syncthreads();   // B2: stats partials + softmax coefs visible

    // ---- contraction, streamed: p[ct4] += coef * (rs*hid + nm) per row-slot ----
    float p0 = 0.f, p1 = 0.f, p2 = 0.f, p3 = 0.f;
    #pragma unroll
    for (int r = 0; r < 16; ++r){
      int row = rg * 32 + (r & 3) + ((r >> 2) << 3) + (hi5 << 2);
      float st = snqS[row * 2] + snqS[row * 2 + 1];
      float qt = snqQ[row * 2] + snqQ[row * 2 + 1];
      float m  = st * (1.f / 256.f);
      float var = qt * (1.f / 256.f) - m * m;
      float rs = rsqrtf(fmaxf(var, 0.f) + 1e-5f);
      float nm = -rs * m;
      const float* cb = coefT + cg * 4 * 257 + row;   // heads 4cg..4cg+3
      p0 = fmaf(cb[0 * 257], fmaf(rs, acc[0][r], nm), p0);
      p1 = fmaf(cb[1 * 257], fmaf(rs, acc[1][r], nm), p1);
      p2 = fmaf(cb[2 * 257], fmaf(rs, acc[2][r], nm), p2);
      p3 = fmaf(cb[3 * 257], fmaf(rs, acc[3][r], nm), p3);
    }
    p0 += __shfl_xor(p0, 32);
    p1 += __shfl_xor(p1, 32);
    p2 += __shfl_xor(p2, 32);
    p3 += __shfl_xor(p3, 32);
    if (l < 32){
      outp[w * 128 +  0 + c32] = p0;
      outp[w * 128 + 32 + c32] = p1;
      outp[w * 128 + 64 + c32] = p2;
      outp[w * 128 + 96 + c32] = p3;
    }
    __syncthreads();   // B3: outp partials visible

    // ---- cross-rowgroup reduce, apply gamma/beta, f32 store ----
    if (tid < 256){
      int cgc = tid >> 7, ci = tid & 127;
      float S = 0.f;
      #pragma unroll
      for (int r8 = 0; r8 < 8; ++r8) S += outp[(r8 * 2 + cgc) * 128 + ci];
      out[((size_t)x << 8) + tid] = fmaf(ldsG[tid], S, ldsBt[tid]);
    }
  }
}

extern "C" void kernel_launch(void* const* d_in, const int* in_sizes, int n_in,
                              void* d_out, int out_size, void* d_ws, size_t ws_size,
                              hipStream_t stream){
  (void)in_sizes; (void)n_in; (void)out_size; (void)d_ws; (void)ws_size;
  const float* xy    = (const float*)d_in[0];
  const int*   mask  = (const int*)d_in[1];
  const float* W1    = (const float*)d_in[2];
  const float* b1    = (const float*)d_in[3];
  const float* gamma = (const float*)d_in[4];
  const float* beta  = (const float*)d_in[5];
  const float* W2    = (const float*)d_in[6];
  const float* b2    = (const float*)d_in[7];

  hipFuncSetAttribute((const void*)attn_main,
                      hipFuncAttributeMaxDynamicSharedMemorySize, (int)LDS_BYTES);
  attn_main<<<NBLK, 1024, LDS_BYTES, stream>>>(xy, mask, W1, b1, gamma, beta, W2, b2,
                                               (float*)d_out);
}

// Round 14
// 126.124 us; speedup vs baseline: 2.0379x; 2.0379x over previous
//
#include <hip/hip_runtime.h>
#include <stdint.h>
#include <stddef.h>

// Problem: X=2048, Y=256, F=128, H=8, NF=32, O=H*NF=256. f32 I/O, mask int32.
//
// Round 14: dual-group phase-offset pipeline on the round-8 base (101 us).
//  - 1024 thr = 16 waves = 2 groups x 8 waves. Group 0 -> even x, group 1 -> odd x,
//    offset by 3 slots of a 6-slot schedule, so every barrier interval pairs one
//    group's GEMM with the other group's convert/softmax/reduce (pipe overlap).
//  - Each group does a full x as TWO 128-row halves; per half each wave owns
//    16 rows x 256 cols with f32x4 acc[16] = 64 AGPR, reused across halves.
//    (f32x16 is banned: r11-r13 proved it always spills; f32x4 r8/r4 are clean.)
//  - Math identical to round 8: f16 single-pass MFMA, wave-local LN butterfly,
//    algebraic gamma/beta fold. Buffers duplicated per group (coefT, outp).

typedef __attribute__((ext_vector_type(8))) _Float16 f16x8;  // 4 VGPRs
typedef __attribute__((ext_vector_type(8))) float f32x8;
typedef __attribute__((ext_vector_type(4))) float f32x4;

#define XPB 8
#define NBLK 256

// dynamic LDS layout (bytes) — total 105600 < 163840
#define OFF_W1    0u        // 65536: W1 f16 fragments [(nt*4+kk)][l][8]
#define OFF_W2    65536u    // 4096 : W2 f16 fragments [kk][l][8] (cols 8..15 = 0)
#define OFF_COEF0 69632u    // 8224 : float[8][257] group-0 logits/coefs
#define OFF_COEF1 77856u    // 8224 : float[8][257] group-1
#define OFF_OUTP0 86080u    // 8192 : float[8][256] group-0 partials
#define OFF_OUTP1 94272u    // 8192 : float[8][256] group-1
#define OFF_B1    102464u   // 1024 : float[256]
#define OFF_G     103488u   // 1024
#define OFF_BT    104512u   // 1024
#define OFF_B2    105536u   // 64   : float[16]
#define LDS_BYTES 105600u

__device__ __forceinline__ f32x4 mfma16(f16x8 a, f16x8 b, f32x4 c){
  return __builtin_amdgcn_mfma_f32_16x16x32_f16(a, b, c, 0, 0, 0);
}

__global__ __launch_bounds__(1024, 4) void attn_main(
    const float* __restrict__ xy, const int* __restrict__ mask,
    const float* __restrict__ W1g, const float* __restrict__ b1g,
    const float* __restrict__ gammag, const float* __restrict__ betag,
    const float* __restrict__ W2g, const float* __restrict__ b2g,
    float* __restrict__ out)
{
  extern __shared__ char smem[];
  const int tid = threadIdx.x;
  const int l  = tid & 63;
  const int w  = tid >> 6;     // wave 0..15
  const int g  = w >> 3;       // group 0/1
  const int wg = w & 7;        // wave in group
  const int lg = l >> 4;       // lane group 0..3
  const int lc = l & 15;

  _Float16* w1f = (_Float16*)(smem + OFF_W1);
  _Float16* w2f = (_Float16*)(smem + OFF_W2);
  float* coefT = (float*)(smem + (g ? OFF_COEF1 : OFF_COEF0));  // [8][257]
  float* outp  = (float*)(smem + (g ? OFF_OUTP1 : OFF_OUTP0));  // [8][256]
  float* ldsB1 = (float*)(smem + OFF_B1);
  float* ldsG  = (float*)(smem + OFF_G);
  float* ldsBt = (float*)(smem + OFF_BT);
  float* ldsB2 = (float*)(smem + OFF_B2);

  if (tid < 256){
    ldsB1[tid] = b1g[tid];
    ldsG[tid]  = gammag[tid];
    ldsBt[tid] = betag[tid];
  }
  if (tid < 16) ldsB2[tid] = (tid < 8) ? b2g[tid] : 0.f;

  // ---- gather W1 (f32) -> f16 16x16 fragment order (r8-verified):
  //      idx=((nt*4+kk)*64+l)*8+j, value=W1[f][o], f=kk*32+(l>>4)*8+j, o=nt*16+(l&15)
  #pragma unroll
  for (int i = 0; i < 4; ++i){
    int base = i * 8192 + tid * 8;
    int bl  = (base >> 3) & 63;
    int bkk = (base >> 9) & 3;
    int bnt = base >> 11;
    int o   = bnt * 16 + (bl & 15);
    int f0  = bkk * 32 + ((bl >> 4) << 3);
    f16x8 v;
    #pragma unroll
    for (int j = 0; j < 8; ++j) v[j] = (_Float16)W1g[(size_t)(f0 + j) * 256 + o];
    *(f16x8*)(w1f + base) = v;
  }
  if (tid < 256){
    int base = tid * 8;
    int bl  = (base >> 3) & 63;
    int bkk = base >> 9;
    int h   = bl & 15;
    int f0  = bkk * 32 + ((bl >> 4) << 3);
    f16x8 v;
    #pragma unroll
    for (int j = 0; j < 8; ++j)
      v[j] = (h < 8) ? (_Float16)W2g[(size_t)(f0 + j) * 8 + h] : (_Float16)0.f;
    *(f16x8*)(w2f + base) = v;
  }
  __syncthreads();   // gathers + params visible

  const int x0 = blockIdx.x * XPB;

  f16x8 ah1[4], ah2[4];
  int mk[4];

  // ---- phase helpers (r8 code with w -> (half, wg) row substitution) ----
  auto CONV = [&](int x, int half, f16x8* ah){
    #pragma unroll
    for (int kk = 0; kk < 4; ++kk){
      f32x8 v = *(const f32x8*)(xy + (((size_t)x * 256 + half * 128 + wg * 16 + lc) << 7)
                                   + kk * 32 + (lg << 3));
      f16x8 vh;
      #pragma unroll
      for (int j = 0; j < 8; ++j){
        float f = fmaxf(v[j], 0.f) + 0.01f * fminf(v[j], 0.f);
        vh[j] = (_Float16)f;
      }
      ah[kk] = vh;
    }
  };
  auto LOGITS = [&](const f16x8* ah, int half){
    f32x4 la = {0.f,0.f,0.f,0.f};
    #pragma unroll
    for (int kk = 0; kk < 4; ++kk){
      f16x8 wb = *(const f16x8*)(w2f + (kk * 64 + l) * 8);
      la = mfma16(ah[kk], wb, la);
    }
    if (lc < 8){
      float b2v = ldsB2[lc];
      #pragma unroll
      for (int r = 0; r < 4; ++r){
        int row = half * 128 + (wg << 4) + (lg << 2) + r;  // C/D: row=(l>>4)*4+r, col=l&15
        coefT[lc * 257 + row] = la[r] + b2v;
      }
    }
  };
  auto MASKLD = [&](int x){
    #pragma unroll
    for (int k = 0; k < 4; ++k) mk[k] = mask[(x << 8) + (k << 6) + l];
  };
  auto SOFTMAX = [&](){
    float lgv[4];
    #pragma unroll
    for (int k = 0; k < 4; ++k){
      float v = coefT[wg * 257 + (k << 6) + l];
      lgv[k] = mk[k] ? 0.f : v;
    }
    float mx = fmaxf(fmaxf(lgv[0], lgv[1]), fmaxf(lgv[2], lgv[3]));
    #pragma unroll
    for (int mm = 1; mm < 64; mm <<= 1) mx = fmaxf(mx, __shfl_xor(mx, mm));
    float e[4]; float sum = 0.f;
    #pragma unroll
    for (int k = 0; k < 4; ++k){ e[k] = __expf(lgv[k] - mx); sum += e[k]; }
    #pragma unroll
    for (int mm = 1; mm < 64; mm <<= 1) sum += __shfl_xor(sum, mm);
    float inv = 1.f / sum;
    #pragma unroll
    for (int k = 0; k < 4; ++k) coefT[wg * 257 + (k << 6) + l] = e[k] * inv;
  };
  auto GEMMC = [&](const f16x8* ah, int half){
    f32x4 acc[16];
    #pragma unroll
    for (int nt = 0; nt < 16; ++nt) acc[nt] = (f32x4){0.f,0.f,0.f,0.f};
    #pragma unroll
    for (int nt = 0; nt < 16; ++nt){
      #pragma unroll
      for (int kk = 0; kk < 4; ++kk){
        f16x8 b = *(const f16x8*)(w1f + ((nt * 4 + kk) * 64 + l) * 8);
        acc[nt] = mfma16(ah[kk], b, acc[nt]);
      }
    }
    // hid = acc + b1; wave-local LN stats (butterfly over lc bits 1,2,4,8)
    float s[4] = {0.f,0.f,0.f,0.f}, q[4] = {0.f,0.f,0.f,0.f};
    #pragma unroll
    for (int nt = 0; nt < 16; ++nt){
      float bv = ldsB1[nt * 16 + lc];
      #pragma unroll
      for (int r = 0; r < 4; ++r){
        float v = acc[nt][r] + bv;
        acc[nt][r] = v;
        s[r] += v;
        q[r] = fmaf(v, v, q[r]);
      }
    }
    #pragma unroll
    for (int mm = 1; mm <= 8; mm <<= 1){
      #pragma unroll
      for (int r = 0; r < 4; ++r){
        s[r] += __shfl_xor(s[r], mm);
        q[r] += __shfl_xor(q[r], mm);
      }
    }
    float mu[4], rstd[4];
    #pragma unroll
    for (int r = 0; r < 4; ++r){
      float m = s[r] * (1.f / 256.f);
      float var = q[r] * (1.f / 256.f) - m * m;
      mu[r] = m;
      rstd[r] = rsqrtf(fmaxf(var, 0.f) + 1e-5f);
    }
    // contraction: partial[col] = sum_{wave rows} coef*rstd*(hid - mu)
    #pragma unroll
    for (int h = 0; h < 8; ++h){
      float c2[4];
      float Dl = 0.f;
      #pragma unroll
      for (int r = 0; r < 4; ++r){
        float c = coefT[h * 257 + half * 128 + (wg << 4) + (lg << 2) + r];
        float v = c * rstd[r];
        c2[r] = v;
        Dl = fmaf(v, mu[r], Dl);
      }
      #pragma unroll
      for (int t = 0; t < 2; ++t){
        int nt = h * 2 + t;               // cols nt*16+lc belong to head nt>>1 == h
        float p = -Dl;
        #pragma unroll
        for (int r = 0; r < 4; ++r) p = fmaf(c2[r], acc[nt][r], p);
        p += __shfl_xor(p, 16);
        p += __shfl_xor(p, 32);
        if (lg == 0){
          int o = wg * 256 + nt * 16 + lc;
          if (half == 0) outp[o] = p; else outp[o] += p;
        }
      }
    }
  };
  auto REDUCE = [&](int x){
    int t5 = tid & 511;
    if (t5 < 256){
      float S = 0.f;
      #pragma unroll
      for (int ww = 0; ww < 8; ++ww) S += outp[ww * 256 + t5];
      out[((size_t)x << 8) + t5] = fmaf(ldsG[t5], S, ldsBt[t5]);
    }
  };

  // ---- 6-slot schedule, groups offset by 3 slots ----
  #pragma clang loop unroll(disable)
  for (int i = 0; i < XPB / 2; ++i){
    const int xe = x0 + 2 * i;      // group-0 x this super-iteration
    const int xo = xe + 1;          // group-1 conv x
    const int xop = xe - 1;         // group-1 GEMM/reduce x (previous super-iter)

    // slot 0: G0 conv+logits h1 | G1 GEMM+contract h1 (prev x)
    if (g == 0){ CONV(xe, 0, ah1); LOGITS(ah1, 0); }
    else if (i > 0){ GEMMC(ah1, 0); }
    __syncthreads();
    // slot 1: G0 conv+logits h2 + mask | G1 GEMM+contract h2
    if (g == 0){ CONV(xe, 1, ah2); LOGITS(ah2, 1); MASKLD(xe); }
    else if (i > 0){ GEMMC(ah2, 1); }
    __syncthreads();
    // slot 2: G0 softmax | G1 reduce+store (prev x)
    if (g == 0){ SOFTMAX(); }
    else if (i > 0){ REDUCE(xop); }
    __syncthreads();
    // slot 3: G0 GEMM+contract h1 | G1 conv+logits h1
    if (g == 0){ GEMMC(ah1, 0); }
    else { CONV(xo, 0, ah1); LOGITS(ah1, 0); }
    __syncthreads();
    // slot 4: G0 GEMM+contract h2 | G1 conv+logits h2 + mask
    if (g == 0){ GEMMC(ah2, 1); }
    else { CONV(xo, 1, ah2); LOGITS(ah2, 1); MASKLD(xo); }
    __syncthreads();
    // slot 5: G0 reduce+store | G1 softmax
    if (g == 0){ REDUCE(xe); }
    else { SOFTMAX(); }
    __syncthreads();
  }
  // epilogue: group 1 finishes its last x (= x0 + XPB - 1)
  if (g == 1) GEMMC(ah1, 0);
  __syncthreads();
  if (g == 1) GEMMC(ah2, 1);
  __syncthreads();
  if (g == 1) REDUCE(x0 + XPB - 1);
}

extern "C" void kernel_launch(void* const* d_in, const int* in_sizes, int n_in,
                              void* d_out, int out_size, void* d_ws, size_t ws_size,
                              hipStream_t stream){
  (void)in_sizes; (void)n_in; (void)out_size; (void)d_ws; (void)ws_size;
  const float* xy    = (const float*)d_in[0];
  const int*   mask  = (const int*)d_in[1];
  const float* W1    = (const float*)d_in[2];
  const float* b1    = (const float*)d_in[3];
  const float* gamma = (const float*)d_in[4];
  const float* beta  = (const float*)d_in[5];
  const float* W2    = (const float*)d_in[6];
  const float* b2    = (const float*)d_in[7];

  hipFuncSetAttribute((const void*)attn_main,
                      hipFuncAttributeMaxDynamicSharedMemorySize, (int)LDS_BYTES);
  attn_main<<<NBLK, 1024, LDS_BYTES, stream>>>(xy, mask, W1, b1, gamma, beta, W2, b2,
                                               (float*)d_out);
}